// Round 2
// baseline (355.548 us; speedup 1.0000x reference)
//
#include <hip/hip_runtime.h>
#include <math.h>

constexpr int BATCH = 65536;
constexpr int DIM = 1024;

// tanh^2(y) via fast exp: tanh(y) = 1 - 2/(exp(2y)+1).
// Stable for all y: exp overflow -> +inf -> rcp -> 0 -> h = 1. exp underflow -> 0 -> h = -1.
__device__ __forceinline__ float tanh_sq(float y) {
    float t = __expf(2.0f * y);                 // v_exp_f32 path
    float r = __builtin_amdgcn_rcpf(t + 1.0f);  // fast rcp, ~1 ulp
    float h = 1.0f - 2.0f * r;
    return h * h;
}

// One wave (64 lanes) per row. Lane l handles cols {c*256 + l*4 .. +3} for c in 0..3
// -> float4 loads, wave reads contiguous 1KiB per chunk (perfectly coalesced).
// w/b fragments (16 floats each) preloaded into registers once per wave.
__global__ __launch_bounds__(256) void simplenet_kernel(
        const float* __restrict__ x, const float* __restrict__ w,
        const float* __restrict__ b, float* __restrict__ out, int num_waves) {
    const int lane = threadIdx.x & 63;
    const int gwave = (blockIdx.x * blockDim.x + threadIdx.x) >> 6;

    float4 wv[4], bv[4];
#pragma unroll
    for (int c = 0; c < 4; ++c) {
        const int col = c * 256 + lane * 4;
        wv[c] = *reinterpret_cast<const float4*>(w + col);
        bv[c] = *reinterpret_cast<const float4*>(b + col);
    }

    for (int row = gwave; row < BATCH; row += num_waves) {
        const float4* __restrict__ xr =
            reinterpret_cast<const float4*>(x + (size_t)row * DIM);
        float acc = 0.0f;
#pragma unroll
        for (int c = 0; c < 4; ++c) {
            const float4 xv = xr[c * 64 + lane];
            acc += tanh_sq(fmaf(xv.x, wv[c].x, bv[c].x));
            acc += tanh_sq(fmaf(xv.y, wv[c].y, bv[c].y));
            acc += tanh_sq(fmaf(xv.z, wv[c].z, bv[c].z));
            acc += tanh_sq(fmaf(xv.w, wv[c].w, bv[c].w));
        }
        // 64-lane butterfly reduce
#pragma unroll
        for (int off = 32; off; off >>= 1) acc += __shfl_xor(acc, off);
        if (lane == 0) out[row] = acc;
    }
}

extern "C" void kernel_launch(void* const* d_in, const int* in_sizes, int n_in,
                              void* d_out, int out_size, void* d_ws, size_t ws_size,
                              hipStream_t stream) {
    const float* x = (const float*)d_in[0];
    const float* w = (const float*)d_in[1];
    const float* b = (const float*)d_in[2];
    float* out = (float*)d_out;

    constexpr int threads = 256;
    constexpr int blocks = 2048;                    // ~8 blocks/CU, grid-stride the rest
    constexpr int num_waves = blocks * (threads / 64);
    simplenet_kernel<<<blocks, threads, 0, stream>>>(x, w, b, out, num_waves);
}